// Round 1
// baseline (52.589 us; speedup 1.0000x reference)
//
#include <hip/hip_runtime.h>
#include <hip/hip_bf16.h>

#define NROWS 8192
#define DIM   128
#define NT    64                  // NROWS / 128 tiles per dim
#define NBLK  (NT * (NT + 1) / 2) // 2080 triangle tiles
#define TOTAL_OUT 33550336u       // NROWS*(NROWS-1)/2

typedef short bf16x8 __attribute__((ext_vector_type(8)));   // 8 bf16 in 4 VGPRs
typedef float f32x4  __attribute__((ext_vector_type(4)));
typedef unsigned short u16x8 __attribute__((ext_vector_type(8)));

// fp32 -> bf16 round-to-nearest-even (bit trick; inputs are finite gaussians)
static __device__ inline unsigned short f32_to_bf16(float f) {
    unsigned int u = __float_as_uint(f);
    u += 0x7FFFu + ((u >> 16) & 1u);
    return (unsigned short)(u >> 16);
}

// One wave per row: convert row to bf16, compute squared norm.
__global__ __launch_bounds__(64) void prep_kernel(const float* __restrict__ X,
                                                  unsigned short* __restrict__ Xb,
                                                  float* __restrict__ sq,
                                                  float* __restrict__ out) {
    const int row  = blockIdx.x;
    const int lane = threadIdx.x; // 0..63, 2 elements each
    const float2 v = *reinterpret_cast<const float2*>(X + (size_t)row * DIM + lane * 2);
    unsigned int packed = ((unsigned int)f32_to_bf16(v.y) << 16) | f32_to_bf16(v.x);
    *reinterpret_cast<unsigned int*>(Xb + (size_t)row * DIM + lane * 2) = packed;
    float s = v.x * v.x + v.y * v.y;
    #pragma unroll
    for (int o = 32; o > 0; o >>= 1) s += __shfl_xor(s, o);
    if (lane == 0) sq[row] = s;
    if (row == 0 && lane == 0) out[TOTAL_OUT - 1] = 0.0f; // skipped slot stacks as zero
}

// Triangle-tiled bf16 MFMA: C_tile = Xl (128xK) * Xu^T (Kx128), K=128 one-shot.
// dist = sq[l] + sq[u] - 2*dot, scattered to out[u*(u-1)/2 - 1 + l].
__global__ __launch_bounds__(256, 2) void pdist_kernel(const unsigned short* __restrict__ Xb,
                                                       const float* __restrict__ sq,
                                                       float* __restrict__ out) {
    __shared__ char smem[65536];
    char* ldsA = smem;           // 128 rows x 256B (swizzled)
    char* ldsB = smem + 32768;

    const int t  = threadIdx.x;
    const int bt = blockIdx.x;
    // decode triangle index: bt = bj*(bj+1)/2 + bi, bi <= bj
    int bj = (int)((sqrtf(8.0f * (float)bt + 1.0f) - 1.0f) * 0.5f);
    while ((bj + 1) * (bj + 2) / 2 <= bt) ++bj;
    while (bj * (bj + 1) / 2 > bt) --bj;
    const int bi = bt - bj * (bj + 1) / 2;

    // ---- stage both tiles into LDS with XOR swizzle (write side) ----
    const unsigned short* srcA = Xb + (size_t)bi * 128 * DIM;
    const unsigned short* srcB = Xb + (size_t)bj * 128 * DIM;
    #pragma unroll
    for (int i = 0; i < 8; ++i) {
        int chunk = t + i * 256;       // 0..2047 chunks of 16B
        int row   = chunk >> 4;        // 16 chunks per 256B row
        int c     = chunk & 15;
        int sc    = c ^ (row & 7);     // swizzle
        *reinterpret_cast<u16x8*>(ldsA + row * 256 + sc * 16) =
            *reinterpret_cast<const u16x8*>(srcA + row * DIM + c * 8);
        *reinterpret_cast<u16x8*>(ldsB + row * 256 + sc * 16) =
            *reinterpret_cast<const u16x8*>(srcB + row * DIM + c * 8);
    }
    __syncthreads();

    const int wid  = t >> 6;
    const int lane = t & 63;
    const int wr   = wid >> 1;   // wave row (l dim), 0..1
    const int wc   = wid & 1;    // wave col (u dim), 0..1
    const int lrow = lane & 15;
    const int kgrp = lane >> 4;  // 0..3 -> k offset 8*kgrp within K=32 step

    f32x4 acc[4][4];
    const f32x4 fzero = {0.f, 0.f, 0.f, 0.f};
    #pragma unroll
    for (int m = 0; m < 4; ++m)
        #pragma unroll
        for (int n = 0; n < 4; ++n) acc[m][n] = fzero;

    #pragma unroll
    for (int kk = 0; kk < 4; ++kk) {   // 4 K-steps of 32
        const int chunk = kk * 4 + kgrp;
        bf16x8 a[4], b[4];
        #pragma unroll
        for (int m = 0; m < 4; ++m) {
            int row = wr * 64 + m * 16 + lrow;
            a[m] = *reinterpret_cast<const bf16x8*>(ldsA + row * 256 + (chunk ^ (row & 7)) * 16);
        }
        #pragma unroll
        for (int n = 0; n < 4; ++n) {
            int row = wc * 64 + n * 16 + lrow;
            b[n] = *reinterpret_cast<const bf16x8*>(ldsB + row * 256 + (chunk ^ (row & 7)) * 16);
        }
        #pragma unroll
        for (int m = 0; m < 4; ++m)
            #pragma unroll
            for (int n = 0; n < 4; ++n)
                acc[m][n] = __builtin_amdgcn_mfma_f32_16x16x32_bf16(a[m], b[n], acc[m][n], 0, 0, 0);
    }

    // ---- epilogue: dist = sq[l] + sq[u] - 2*acc, scatter to triangle ----
    const int l0 = bi * 128 + wr * 64;
    const int u0 = bj * 128 + wc * 64;
    const int rj = kgrp * 4;     // C row offset within fragment: row = rj + j

    float squ[4];
    f32x4 sql[4];
    #pragma unroll
    for (int n = 0; n < 4; ++n) squ[n] = sq[u0 + n * 16 + lrow];
    #pragma unroll
    for (int m = 0; m < 4; ++m)
        sql[m] = *reinterpret_cast<const f32x4*>(sq + l0 + m * 16 + rj);

    if (bi != bj) {
        // fully below diagonal: every element valid, u >= 128
        #pragma unroll
        for (int m = 0; m < 4; ++m) {
            #pragma unroll
            for (int n = 0; n < 4; ++n) {
                const int u = u0 + n * 16 + lrow;
                const size_t base = ((size_t)u * (u - 1)) / 2 - 1 + (size_t)(l0 + m * 16 + rj);
                f32x4 d;
                #pragma unroll
                for (int j = 0; j < 4; ++j) d[j] = sql[m][j] + squ[n] - 2.0f * acc[m][n][j];
                __builtin_memcpy(out + base, &d, 16); // 4B-aligned 16B store
            }
        }
    } else {
        // diagonal tile: mask l < u && u >= 2
        #pragma unroll
        for (int m = 0; m < 4; ++m) {
            #pragma unroll
            for (int n = 0; n < 4; ++n) {
                const int u = u0 + n * 16 + lrow;
                #pragma unroll
                for (int j = 0; j < 4; ++j) {
                    const int l = l0 + m * 16 + rj + j;
                    if (l < u && u >= 2) {
                        out[((size_t)u * (u - 1)) / 2 - 1 + l] = sql[m][j] + squ[n] - 2.0f * acc[m][n][j];
                    }
                }
            }
        }
    }
}

extern "C" void kernel_launch(void* const* d_in, const int* in_sizes, int n_in,
                              void* d_out, int out_size, void* d_ws, size_t ws_size,
                              hipStream_t stream) {
    const float* X = (const float*)d_in[0];
    float* out = (float*)d_out;
    unsigned short* Xb = (unsigned short*)d_ws;                       // 2 MB bf16
    float* sq = (float*)((char*)d_ws + (size_t)NROWS * DIM * 2);      // 32 KB norms

    prep_kernel<<<NROWS, 64, 0, stream>>>(X, Xb, sq, out);
    pdist_kernel<<<NBLK, 256, 0, stream>>>(Xb, sq, out);
}